// Round 17
// baseline (120.839 us; speedup 1.0000x reference)
//
#include <hip/hip_runtime.h>
#include <math.h>

typedef unsigned short u16;
typedef __attribute__((ext_vector_type(4))) float f32x4;
typedef __attribute__((ext_vector_type(8))) short s16x8;
typedef __attribute__((ext_vector_type(8))) _Float16 f16x8;

__device__ __forceinline__ u16 f2bf(float f){
  unsigned u = __builtin_bit_cast(unsigned, f);
  u += 0x7fffu + ((u >> 16) & 1u);
  return (u16)(u >> 16);
}
__device__ __forceinline__ float bf2f(u16 h){
  unsigned u = ((unsigned)h) << 16;
  return __builtin_bit_cast(float, u);
}
__device__ __forceinline__ u16 f2h(float f){
  return __builtin_bit_cast(u16, (_Float16)f);
}
__device__ __forceinline__ float h2f(u16 h){
  return (float)__builtin_bit_cast(_Float16, h);
}
__device__ __forceinline__ f32x4 mfma16h(f16x8 a, f16x8 b, f32x4 c){
  return __builtin_amdgcn_mfma_f32_16x16x32_f16(a, b, c, 0, 0, 0);
}
__device__ __forceinline__ void gload16(const void* src, const u16* ldsbase){
  __builtin_amdgcn_global_load_lds(
      (const __attribute__((address_space(1))) void*)src,
      (__attribute__((address_space(3))) void*)ldsbase, 16, 0, 0);
}

// ---- fused preprocessing: x -> A-frags ; Wqkv -> B-frags ; Wo -> B-frags ----
__global__ __launch_bounds__(256) void k_pre(const float* __restrict__ x,
    const float* __restrict__ Wq, const float* __restrict__ Wo,
    u16* __restrict__ Afq, u16* __restrict__ Bq1, u16* __restrict__ Bq2){
  __shared__ float tile[64][65];
  int b = blockIdx.x, t = threadIdx.x;
  if (b < 1024){
    int id = b*256 + t;                       // 262144
    int row = id>>7, k0 = (id&127)*8;
    const float4* xp = (const float4*)(x + (size_t)row*1024 + k0);
    float4 v0 = xp[0], v1 = xp[1];
    float vv[8] = {v0.x,v0.y,v0.z,v0.w, v1.x,v1.y,v1.z,v1.w};
    u16 hh[8];
    #pragma unroll
    for (int e=0; e<8; ++e) hh[e] = f2h(vv[e]);
    int mt = row>>7, ms = (row>>4)&7, m16 = row&15;
    int kt = k0>>6, ks2 = (k0>>5)&1, lg = (k0>>3)&3;
    int lane = lg*16 + m16;
    size_t base = (size_t)(mt*16 + kt)*8192;
    *(uint4*)&Afq[base + (size_t)(ks2*8 + ms)*512 + lane*8] = *(uint4*)hh;
    return;
  }
  const float* in; u16* Bfq; int N, nKt, nt, kt;
  if (b < 1360){
    int bb = b - 1024; nt = bb % 21; kt = bb / 21;
    in = Wq; Bfq = Bq1; N = 1344; nKt = 16;
  } else {
    int bb = b - 1360; nt = bb % 16; kt = bb / 16;
    in = Wo; Bfq = Bq2; N = 1024; nKt = 24;
  }
  #pragma unroll
  for (int i=0; i<16; ++i){
    int idx = i*256 + t;
    int r = idx>>6, c = idx&63;
    tile[r][c] = in[(size_t)(kt*64 + r)*N + nt*64 + c];
  }
  __syncthreads();
  size_t base = (size_t)(nt*nKt + kt)*4096;
  #pragma unroll
  for (int j=0; j<2; ++j){
    int idx = j*256 + t;
    int np = idx>>3, ko = idx&7;
    u16 hh[8];
    #pragma unroll
    for (int e=0; e<8; ++e) hh[e] = f2h(tile[ko*8+e][np]);
    int ks2 = ko>>2, lg = ko&3, ns = np>>4, n16 = np&15;
    int lane = lg*16 + n16;
    *(uint4*)&Bfq[base + (size_t)(ks2*4 + ns)*512 + lane*8] = *(uint4*)hh;
  }
}

// ---- pairwise bias v4: coalesced gelu pass -> swizzled f16 LDS -> MFMA matvec ----
// Granule swizzle g^=(g>>4)&7 identical on write/read (row&7 == (g>>4)&7).
__global__ __launch_bounds__(256,4) void k_bias4(const float* __restrict__ pw,
    const float* __restrict__ rv, const float* __restrict__ gamma,
    const float* __restrict__ beta, const float* __restrict__ Wb,
    u16* __restrict__ biash){
  __shared__ float As[128], Bs[128];
  __shared__ u16 WbS[2048];        // [ks][lane][8] fp16 B-fragments
  __shared__ u16 G[16384];         // gelu f16 [128 pairs][128 ch], swizzled
  int t = threadIdx.x;
  if (t < 128){
    As[t] = 11.313708498984761f * rsqrtf(fmaxf(rv[t], 1e-5f)) * (gamma[t] + 1.0f);
    Bs[t] = beta[t];
  }
  {
    int ks = t>>6, lane2 = t&63, lg2 = lane2>>4, lr2 = lane2&15;
    #pragma unroll
    for (int e=0; e<8; ++e){
      float v = (lr2 < 8) ? Wb[(ks*32 + lg2*8 + e)*8 + lr2] : 0.0f;
      WbS[ks*512 + lane2*8 + e] = f2h(v);
    }
  }
  __syncthreads();
  size_t base = (size_t)blockIdx.x*16384;
  // coalesced gelu: 8 passes x 256 threads x 8 contiguous floats
  #pragma unroll
  for (int ps=0; ps<8; ++ps){
    int o = ps*2048 + t*8;           // element offset within tile (f16 units too)
    const float4* sp = (const float4*)(pw + base + o);
    float4 x0 = sp[0], x1 = sp[1];
    int c = o & 127;
    float4 a0 = *(const float4*)&As[c], a1 = *(const float4*)&As[c+4];
    float4 b0 = *(const float4*)&Bs[c], b1 = *(const float4*)&Bs[c+4];
    float xv[8] = {x0.x*a0.x+b0.x, x0.y*a0.y+b0.y, x0.z*a0.z+b0.z, x0.w*a0.w+b0.w,
                   x1.x*a1.x+b1.x, x1.y*a1.y+b1.y, x1.z*a1.z+b1.z, x1.w*a1.w+b1.w};
    f16x8 gh;
    #pragma unroll
    for (int e=0; e<8; ++e){
      float v = xv[e];
      float z = v * 0.7071067811865476f;
      float s = fabsf(z);
      float den = 1.0f + 0.3275911f*s;
      float tt; asm("v_rcp_f32 %0, %1" : "=v"(tt) : "v"(den));
      float poly = ((((1.061405429f*tt - 1.453152027f)*tt + 1.421413741f)*tt - 0.284496736f)*tt + 0.254829592f)*tt;
      float E = __expf(-s*s);
      float Q = 0.5f*v*poly*E;
      float ge = (v >= 0.0f) ? (v - Q) : Q;
      gh[e] = (_Float16)ge;
    }
    int g = o >> 3;
    int gs = g ^ ((g>>4)&7);
    *(uint4*)&G[gs<<3] = __builtin_bit_cast(uint4, gh);
  }
  __syncthreads();
  // MFMA matvec from LDS fragments
  int w = t>>6, lane = t&63, lg = lane>>4, lr = lane&15;
  #pragma unroll
  for (int it=0; it<2; ++it){
    int rloc = it*64 + w*16;
    f32x4 acc = {0.f,0.f,0.f,0.f};
    #pragma unroll
    for (int ks=0; ks<4; ++ks){
      int o = (rloc + lr)*128 + ks*32 + lg*8;
      int g = o >> 3;
      int gs = g ^ ((g>>4)&7);
      f16x8 gh = *(const f16x8*)&G[gs<<3];
      f16x8 bh = *(const f16x8*)&WbS[ks*512 + lane*8];
      acc = mfma16h(gh, bh, acc);
    }
    if (lr < 8)
      #pragma unroll
      for (int r=0; r<4; ++r)
        biash[(size_t)(blockIdx.x*128 + rloc + lg*4 + r)*8 + lr] = f2h(acc[r]);
  }
}

// ---- norm+rope only: one wave per (row n, group g): g=0..7 Q, g=8 K, g=9 V ----
__global__ __launch_bounds__(256) void k_norm(const u16* __restrict__ qkvh,
   const float* __restrict__ rot, const float* __restrict__ qw, const float* __restrict__ kw,
   const float* __restrict__ vw, u16* __restrict__ Qf, u16* __restrict__ KVF){
  int t = threadIdx.x;
  int w = t>>6, l = t&63;
  int task = blockIdx.x*4 + w;          // 20480 tasks
  int n = task/10, g = task - (task/10)*10;
  const u16* row = qkvh + (size_t)n*1344;
  size_t tbase = (size_t)(n>>5)*10240;
  if (g < 9){
    float e0 = h2f(row[g*128 + l]);
    float e1 = h2f(row[g*128 + 64 + l]);
    float s = e0*e0 + e1*e1;
    #pragma unroll
    for (int m=1; m<64; m<<=1) s += __shfl_xor(s, m, 64);
    float rr = rsqrtf(s*(1.0f/128.0f) + 1.1920929e-07f);
    const float* ww = (g < 8) ? qw : kw;
    float sc = (g < 8) ? 0.125f : 1.0f;
    float qn0 = e0*rr*ww[l]*sc;
    float qn1 = e1*rr*ww[64+l]*sc;
    float p0 = rot[(size_t)n*128 + l], p1 = rot[(size_t)n*128 + 64 + l];
    float c0, s0, c1, s1;
    __sincosf(p0, &s0, &c0);
    __sincosf(p1, &s1, &c1);
    float o0 = qn0*c0 - qn1*s0;
    float o1 = qn1*c1 + qn0*s1;
    if (g < 8){
      Qf[((size_t)g*2048 + n)*128 + l]      = f2h(o0);
      Qf[((size_t)g*2048 + n)*128 + 64 + l] = f2h(o1);
    } else {
      int d0 = l, d1 = 64 + l;
      size_t ka0 = tbase + (size_t)((d0>>5)*2 + ((n>>4)&1))*512
                 + (size_t)(((d0>>3)&3)*16 + (n&15))*8 + (d0&7);
      size_t ka1 = tbase + (size_t)((d1>>5)*2 + ((n>>4)&1))*512
                 + (size_t)(((d1>>3)&3)*16 + (n&15))*8 + (d1&7);
      KVF[ka0] = f2h(o0);
      KVF[ka1] = f2h(o1);
    }
  } else {
    float v0 = h2f(row[1152 + l]);
    float v1 = h2f(row[1152 + 64 + l]);
    float v2 = h2f(row[1152 + 128 + l]);
    float s = v0*v0 + v1*v1 + v2*v2;
    #pragma unroll
    for (int m=1; m<64; m<<=1) s += __shfl_xor(s, m, 64);
    float rr = rsqrtf(s*(1.0f/192.0f) + 1.1920929e-07f);
    int lgv = (n>>3)&3, ev = n&7;
    size_t vbase = tbase + 4096;
    float vals[3] = {v0, v1, v2};
    #pragma unroll
    for (int j=0; j<3; ++j){
      int d = j*64 + l;
      KVF[vbase + (size_t)(d>>4)*512 + (size_t)(lgv*16 + (d&15))*8 + ev]
          = f2h(vals[j]*rr*vw[d]);
    }
  }
}

// ---- generic fragment-major fp16 GEMM, dbuf gload_lds, XCD-swizzled ----
__global__ __launch_bounds__(256,3) void k_gemm2(const u16* __restrict__ Afq,
    const u16* __restrict__ Bfq, void* __restrict__ Cv, int N, int nKt, int halfOut, int NX){
  __shared__ u16 lds[24576];
  int id = blockIdx.x;
  int per = gridDim.x >> 3;                  // gridDim.x % 8 == 0
  int id2 = (id & 7)*per + (id >> 3);
  int by = id2 / NX;
  int bx = id2 - by*NX;
  int t = threadIdx.x;
  int w = t>>6, lane = t&63, lg = lane>>4, lr = lane&15;
  int iw = w&1, jw = w>>1;
  int n0 = bx*64, m0 = by*128;
  const char* srcA = (const char*)(Afq + (size_t)by*nKt*8192);
  const char* srcB = (const char*)(Bfq + (size_t)bx*nKt*4096);
  int wb = w*1024 + lane*16;
  auto stage = [&](int kt, int cur){
    const char* ta = srcA + (size_t)kt*16384;
    const char* tb = srcB + (size_t)kt*8192;
    int ab = cur*12288;
    #pragma unroll
    for (int i=0; i<4; ++i)
      gload16(ta + i*4096 + wb, &lds[ab + ((i*4096 + w*1024)>>1)]);
    #pragma unroll
    for (int i=0; i<2; ++i)
      gload16(tb + i*4096 + wb, &lds[ab + 8192 + ((i*4096 + w*1024)>>1)]);
  };
  f32x4 acc[4][2] = {};
  stage(0, 0);
  __syncthreads();
  int cur = 0;
  for (int kt=0; kt<nKt; ++kt){
    if (kt+1 < nKt) stage(kt+1, cur^1);
    int ab = cur*12288;
    #pragma unroll
    for (int ks2=0; ks2<2; ++ks2){
      f16x8 ah[4], bh[2];
      #pragma unroll
      for (int m=0; m<4; ++m)
        ah[m] = *(const f16x8*)&lds[ab + (size_t)(ks2*8 + iw*4 + m)*512 + lane*8];
      #pragma unroll
      for (int n=0; n<2; ++n)
        bh[n] = *(const f16x8*)&lds[ab + 8192 + (size_t)(ks2*4 + jw*2 + n)*512 + lane*8];
      #pragma unroll
      for (int m=0; m<4; ++m)
        #pragma unroll
        for (int n=0; n<2; ++n)
          acc[m][n] = mfma16h(ah[m], bh[n], acc[m][n]);
    }
    __syncthreads();
    cur ^= 1;
  }
  #pragma unroll
  for (int m=0; m<4; ++m)
    #pragma unroll
    for (int n=0; n<2; ++n)
      #pragma unroll
      for (int r=0; r<4; ++r){
        int row = m0 + iw*64 + m*16 + lg*4 + r;
        int col = n0 + jw*32 + n*16 + lr;
        if (halfOut) ((u16*)Cv)[(size_t)row*N + col] = f2h(acc[m][n][r]);
        else         ((float*)Cv)[(size_t)row*N + col] = acc[m][n][r];
      }
}

// ------------- fused attention v6: fragment-major K/V, gload_lds staging, -------------
// (256,2): accO needs 96 VGPR -- (256,3) spills accumulators (R14 regression).
__global__ __launch_bounds__(256,2) void k_attn6(const u16* __restrict__ Qf,
  const u16* __restrict__ KVF, const u16* __restrict__ biash,
  u16* __restrict__ OP, float* __restrict__ SP){
  __shared__ u16 lds[24576];
  int t = threadIdx.x;
  int w = t>>6, lane = t&63, lg = lane>>4, lr = lane&15;
  int q0 = blockIdx.x*32;
  int h  = blockIdx.y*4 + w;
  int zi = blockIdx.z;
  f16x8 qf[2][4];
  #pragma unroll
  for (int qi=0; qi<2; ++qi){
    const u16* qb = Qf + ((size_t)h*2048 + q0 + qi*16 + lr)*128 + lg*8;
    #pragma unroll
    for (int ks=0; ks<4; ++ks) qf[qi][ks] = *(const f16x8*)(qb + ks*32);
  }
  const char* kvb = (const char*)KVF + (size_t)zi*16*20480;
  int wb = w*1024 + lane*16;
  auto stage = [&](int jt, int cur){
    const char* src = kvb + (size_t)jt*20480;
    gload16(src + wb,         &lds[cur*4096 + (w*1024>>1)]);
    gload16(src + 4096 + wb,  &lds[cur*4096 + 2048 + (w*1024>>1)]);
    gload16(src + 8192 + wb,  &lds[8192 + cur*6144 + (w*1024>>1)]);
    gload16(src + 12288 + wb, &lds[8192 + cur*6144 + 2048 + (w*1024>>1)]);
    gload16(src + 16384 + wb, &lds[8192 + cur*6144 + 4096 + (w*1024>>1)]);
  };
  float bCur[2][2], bNxt[2][2];
  auto loadBias = [&](int jt, float bb[2][2]){
    int jq = (zi*512 + jt*32)>>2;
    #pragma unroll
    for (int qi=0; qi<2; ++qi)
      #pragma unroll
      for (int kj=0; kj<2; ++kj)
        bb[qi][kj] = 0.4f*h2f(biash[((size_t)((q0>>2) + qi*4 + lg)*512 + jq + kj*4 + (lr>>2))*8 + h]);
  };
  stage(0, 0);
  loadBias(0, bCur);
  __syncthreads();
  f32x4 accO[2][12] = {};
  f32x4 accR[2] = {};
  f16x8 vone;
  #pragma unroll
  for (int e=0; e<8; ++e) vone[e] = (_Float16)1.0f;
  int psb = 20480 + w*1024;
  int po0 = lane*8;       po0 ^= ((po0>>6)&7)<<3;
  int po1 = 512 + lane*8; po1 ^= ((po1>>6)&7)<<3;
  int cur = 0;
  for (int jt=0; jt<16; ++jt){
    if (jt < 15){ stage(jt+1, cur^1); loadBias(jt+1, bNxt); }
    f32x4 accS[2][2] = {};
    #pragma unroll
    for (int ks=0; ks<4; ++ks){
      #pragma unroll
      for (int kj=0; kj<2; ++kj){
        f16x8 kb = *(const f16x8*)&lds[cur*4096 + (ks*2+kj)*512 + lane*8];
        accS[0][kj] = mfma16h(qf[0][ks], kb, accS[0][kj]);
        accS[1][kj] = mfma16h(qf[1][ks], kb, accS[1][kj]);
      }
    }
    #pragma unroll
    for (int qi=0; qi<2; ++qi)
      #pragma unroll
      for (int kj=0; kj<2; ++kj){
        float bv = bCur[qi][kj];
        #pragma unroll
        for (int r=0; r<4; ++r){
          float te = __expf(0.4f*accS[qi][kj][r] + bv);
          float ri; asm("v_rcp_f32 %0, %1" : "=v"(ri) : "v"(te + 1.0f));
          float p = __expf(-10.0f*ri);
          int o = qi*512 + ((kj*2 + (lr>>3))*16 + lg*4 + r)*8 + (lr&7);
          o ^= ((o>>6)&7)<<3;
          lds[psb + o] = f2h(p);
        }
      }
    f16x8 pa0 = *(const f16x8*)&lds[psb + po0];
    f16x8 pa1 = *(const f16x8*)&lds[psb + po1];
    #pragma unroll
    for (int df=0; df<12; ++df){
      f16x8 vb = *(const f16x8*)&lds[8192 + cur*6144 + df*512 + lane*8];
      accO[0][df] = mfma16h(pa0, vb, accO[0][df]);
      accO[1][df] = mfma16h(pa1, vb, accO[1][df]);
    }
    accR[0] = mfma16h(pa0, vone, accR[0]);
    accR[1] = mfma16h(pa1, vone, accR[1]);
    __syncthreads();
    cur ^= 1;
    #pragma unroll
    for (int qi=0; qi<2; ++qi){ bCur[qi][0] = bNxt[qi][0]; bCur[qi][1] = bNxt[qi][1]; }
  }
  #pragma unroll
  for (int qi=0; qi<2; ++qi){
    #pragma unroll
    for (int df=0; df<12; ++df)
      #pragma unroll
      for (int r=0; r<4; ++r){
        int q = q0 + qi*16 + lg*4 + r;
        OP[(((size_t)zi*8 + h)*2048 + q)*192 + df*16 + lr] = f2h(accO[qi][df][r]);
      }
    if (lr == 0)
      #pragma unroll
      for (int r=0; r<4; ++r)
        SP[((size_t)zi*8 + h)*2048 + q0 + qi*16 + lg*4 + r] = accR[qi][r];
  }
}

// ---- combine 4 z-partials, normalize, write fragment-major fp16 A-tiles for gemm2 ----
__global__ __launch_bounds__(256) void k_comb2(const u16* __restrict__ OP,
    const float* __restrict__ SP, u16* __restrict__ Ao2){
  int id = blockIdx.x*256 + threadIdx.x;    // 393216
  int hq = id / 24;
  int oct = id - hq*24;
  int d0 = oct*8;
  float inv = 1.0f / (SP[hq] + SP[16384+hq] + SP[32768+hq] + SP[49152+hq]);
  float o[8] = {0,0,0,0,0,0,0,0};
  #pragma unroll
  for (int z=0; z<4; ++z){
    uint4 v = *(const uint4*)&OP[((size_t)z*16384 + hq)*192 + d0];
    const u16* pv = (const u16*)&v;
    #pragma unroll
    for (int e=0; e<8; ++e) o[e] += h2f(pv[e]);
  }
  int h = hq >> 11, q = hq & 2047;
  int col = h*192 + d0;
  int kt = col>>6, ks2 = (col>>5)&1, lg = (col>>3)&3;
  int mt = q>>7, ms = (q>>4)&7, m16 = q&15;
  int lane = lg*16 + m16;
  u16 hh[8];
  #pragma unroll
  for (int e=0; e<8; ++e) hh[e] = f2h(o[e]*inv);
  size_t base = (size_t)(mt*24 + kt)*8192;
  *(uint4*)&Ao2[base + (size_t)(ks2*8 + ms)*512 + lane*8] = *(uint4*)hh;
}

extern "C" void kernel_launch(void* const* d_in, const int* in_sizes, int n_in,
                              void* d_out, int out_size, void* d_ws, size_t ws_size,
                              hipStream_t stream){
  (void)in_sizes; (void)n_in; (void)out_size; (void)ws_size;
  const float* x   = (const float*)d_in[0];
  const float* pwi = (const float*)d_in[1];
  const float* rot = (const float*)d_in[2];
  const float* Wq  = (const float*)d_in[3];
  const float* qw  = (const float*)d_in[4];
  const float* kw  = (const float*)d_in[5];
  const float* vw  = (const float*)d_in[6];
  const float* gm  = (const float*)d_in[7];
  const float* bt  = (const float*)d_in[8];
  const float* rvv = (const float*)d_in[9];
  const float* Wb  = (const float*)d_in[10];
  const float* Wo  = (const float*)d_in[11];
  float* out = (float*)d_out;
  char* ws = (char*)d_ws;
  size_t off = 0;
  auto alloc = [&](size_t bytes)->char*{
    char* p = ws + off; off = (off + bytes + 255) & ~(size_t)255; return p;
  };
  u16*   Axq = (u16*)alloc(16ull*16*8192*2);      // x frag-major fp16 (4 MB)
  u16*   Bq1 = (u16*)alloc(21ull*16*4096*2);      // Wqkv frag-major fp16 (2.75 MB)
  u16*   Bq2 = (u16*)alloc(16ull*24*4096*2);      // Wo frag-major fp16 (3.1 MB)
  u16*   Ao2 = (u16*)alloc(16ull*24*8192*2);      // attn-out frag-major fp16 (6.3 MB)
  u16*   qkvh = (u16*)alloc(2048ull*1344*2);      // qkv fp16 (5.5 MB)
  u16*   Qfb = (u16*)alloc(8ull*2048*128*2);
  u16*   KVF = (u16*)alloc(64ull*10240*2);
  u16*   biash = (u16*)alloc(8ull*512*512*2);     // bias f16 [pair][8] (4.2 MB)
  u16*   OP  = (u16*)alloc(4ull*8*2048*192*2);
  float* SP  = (float*)alloc(4ull*8*2048*4);

  k_bias4<<<2048, 256, 0, stream>>>(pwi, rvv, gm, bt, Wb, biash);
  k_pre<<<1744, 256, 0, stream>>>(x, Wq, Wo, Axq, Bq1, Bq2);
  k_gemm2<<<336, 256, 0, stream>>>(Axq, Bq1, qkvh, 1344, 16, 1, 21);
  k_norm<<<5120, 256, 0, stream>>>(qkvh, rot, qw, kw, vw, Qfb, KVF);
  k_attn6<<<dim3(64, 2, 4), 256, 0, stream>>>(Qfb, KVF, biash, OP, SP);
  k_comb2<<<1536, 256, 0, stream>>>(OP, SP, Ao2);
  k_gemm2<<<256, 256, 0, stream>>>(Ao2, Bq2, out, 1024, 24, 0, 16);
}

// Round 18
// 115.260 us; speedup vs baseline: 1.0484x; 1.0484x over previous
//
#include <hip/hip_runtime.h>
#include <math.h>

typedef unsigned short u16;
typedef __attribute__((ext_vector_type(4))) float f32x4;
typedef __attribute__((ext_vector_type(8))) short s16x8;
typedef __attribute__((ext_vector_type(8))) _Float16 f16x8;

__device__ __forceinline__ u16 f2bf(float f){
  unsigned u = __builtin_bit_cast(unsigned, f);
  u += 0x7fffu + ((u >> 16) & 1u);
  return (u16)(u >> 16);
}
__device__ __forceinline__ float bf2f(u16 h){
  unsigned u = ((unsigned)h) << 16;
  return __builtin_bit_cast(float, u);
}
__device__ __forceinline__ u16 f2h(float f){
  return __builtin_bit_cast(u16, (_Float16)f);
}
__device__ __forceinline__ float h2f(u16 h){
  return (float)__builtin_bit_cast(_Float16, h);
}
__device__ __forceinline__ f32x4 mfma16h(f16x8 a, f16x8 b, f32x4 c){
  return __builtin_amdgcn_mfma_f32_16x16x32_f16(a, b, c, 0, 0, 0);
}
__device__ __forceinline__ void gload16(const void* src, const u16* ldsbase){
  __builtin_amdgcn_global_load_lds(
      (const __attribute__((address_space(1))) void*)src,
      (__attribute__((address_space(3))) void*)ldsbase, 16, 0, 0);
}

// ---- fused preprocessing: x -> A-frags ; Wqkv -> B-frags ; Wo -> B-frags ----
__global__ __launch_bounds__(256) void k_pre(const float* __restrict__ x,
    const float* __restrict__ Wq, const float* __restrict__ Wo,
    u16* __restrict__ Afq, u16* __restrict__ Bq1, u16* __restrict__ Bq2){
  __shared__ float tile[64][65];
  int b = blockIdx.x, t = threadIdx.x;
  if (b < 1024){
    int id = b*256 + t;                       // 262144
    int row = id>>7, k0 = (id&127)*8;
    const float4* xp = (const float4*)(x + (size_t)row*1024 + k0);
    float4 v0 = xp[0], v1 = xp[1];
    float vv[8] = {v0.x,v0.y,v0.z,v0.w, v1.x,v1.y,v1.z,v1.w};
    u16 hh[8];
    #pragma unroll
    for (int e=0; e<8; ++e) hh[e] = f2h(vv[e]);
    int mt = row>>7, ms = (row>>4)&7, m16 = row&15;
    int kt = k0>>6, ks2 = (k0>>5)&1, lg = (k0>>3)&3;
    int lane = lg*16 + m16;
    size_t base = (size_t)(mt*16 + kt)*8192;
    *(uint4*)&Afq[base + (size_t)(ks2*8 + ms)*512 + lane*8] = *(uint4*)hh;
    return;
  }
  const float* in; u16* Bfq; int N, nKt, nt, kt;
  if (b < 1360){
    int bb = b - 1024; nt = bb % 21; kt = bb / 21;
    in = Wq; Bfq = Bq1; N = 1344; nKt = 16;
  } else {
    int bb = b - 1360; nt = bb % 16; kt = bb / 16;
    in = Wo; Bfq = Bq2; N = 1024; nKt = 24;
  }
  #pragma unroll
  for (int i=0; i<16; ++i){
    int idx = i*256 + t;
    int r = idx>>6, c = idx&63;
    tile[r][c] = in[(size_t)(kt*64 + r)*N + nt*64 + c];
  }
  __syncthreads();
  size_t base = (size_t)(nt*nKt + kt)*4096;
  #pragma unroll
  for (int j=0; j<2; ++j){
    int idx = j*256 + t;
    int np = idx>>3, ko = idx&7;
    u16 hh[8];
    #pragma unroll
    for (int e=0; e<8; ++e) hh[e] = f2h(tile[ko*8+e][np]);
    int ks2 = ko>>2, lg = ko&3, ns = np>>4, n16 = np&15;
    int lane = lg*16 + n16;
    *(uint4*)&Bfq[base + (size_t)(ks2*4 + ns)*512 + lane*8] = *(uint4*)hh;
  }
}

// ---- pairwise bias v5: bias3 structure + branch-free tanh-gelu (9 VALU/elem) ----
// (256,6): relax 64-VGPR cap (spill risk) while keeping 24 waves/CU.
__global__ __launch_bounds__(256,6) void k_bias5(const float* __restrict__ pw,
    const float* __restrict__ rv, const float* __restrict__ gamma,
    const float* __restrict__ beta, const float* __restrict__ Wb,
    u16* __restrict__ biash){
  __shared__ float As[128], Bs[128];
  __shared__ u16 WbS[2048];        // [ks][lane][8] fp16 B-fragments
  int t = threadIdx.x;
  if (t < 128){
    As[t] = 11.313708498984761f * rsqrtf(fmaxf(rv[t], 1e-5f)) * (gamma[t] + 1.0f);
    Bs[t] = beta[t];
  }
  {
    int ks = t>>6, lane2 = t&63, lg2 = lane2>>4, lr2 = lane2&15;
    #pragma unroll
    for (int e=0; e<8; ++e){
      float v = (lr2 < 8) ? Wb[(ks*32 + lg2*8 + e)*8 + lr2] : 0.0f;
      WbS[ks*512 + lane2*8 + e] = f2h(v);
    }
  }
  __syncthreads();
  int w = t>>6, lane = t&63, lg = lane>>4, lr = lane&15;
  #pragma unroll
  for (int it=0; it<2; ++it){
    int p0 = blockIdx.x*128 + it*64 + w*16;
    const float* rowp = pw + (size_t)(p0 + lr)*128;
    f32x4 acc = {0.f,0.f,0.f,0.f};
    #pragma unroll
    for (int ks=0; ks<4; ++ks){
      int c = ks*32 + lg*8;
      float4 x0 = *(const float4*)(rowp + c);
      float4 x1 = *(const float4*)(rowp + c + 4);
      float4 a0 = *(const float4*)&As[c], a1 = *(const float4*)&As[c+4];
      float4 b0 = *(const float4*)&Bs[c], b1 = *(const float4*)&Bs[c+4];
      float xv[8] = {x0.x*a0.x+b0.x, x0.y*a0.y+b0.y, x0.z*a0.z+b0.z, x0.w*a0.w+b0.w,
                     x1.x*a1.x+b1.x, x1.y*a1.y+b1.y, x1.z*a1.z+b1.z, x1.w*a1.w+b1.w};
      f16x8 gh;
      #pragma unroll
      for (int e=0; e<8; ++e){
        float v = xv[e];
        // gelu ~ v - v/(exp(2*0.7978845608*(v + 0.044715 v^3)) + 1)
        float u2 = v*v;
        float arg = v*(1.5957691216f + 0.0713548162f*u2);   // 2u
        float te = __expf(arg);
        float ri; asm("v_rcp_f32 %0, %1" : "=v"(ri) : "v"(te + 1.0f));
        float ge = v - v*ri;
        gh[e] = (_Float16)ge;
      }
      f16x8 bh = *(const f16x8*)&WbS[ks*512 + lane*8];
      acc = mfma16h(gh, bh, acc);
    }
    if (lr < 8)
      #pragma unroll
      for (int r=0; r<4; ++r)
        biash[(size_t)(p0 + lg*4 + r)*8 + lr] = f2h(acc[r]);
  }
}

// ---- norm+rope only: one wave per (row n, group g): g=0..7 Q, g=8 K, g=9 V ----
__global__ __launch_bounds__(256) void k_norm(const u16* __restrict__ qkvh,
   const float* __restrict__ rot, const float* __restrict__ qw, const float* __restrict__ kw,
   const float* __restrict__ vw, u16* __restrict__ Qf, u16* __restrict__ KVF){
  int t = threadIdx.x;
  int w = t>>6, l = t&63;
  int task = blockIdx.x*4 + w;          // 20480 tasks
  int n = task/10, g = task - (task/10)*10;
  const u16* row = qkvh + (size_t)n*1344;
  size_t tbase = (size_t)(n>>5)*10240;
  if (g < 9){
    float e0 = h2f(row[g*128 + l]);
    float e1 = h2f(row[g*128 + 64 + l]);
    float s = e0*e0 + e1*e1;
    #pragma unroll
    for (int m=1; m<64; m<<=1) s += __shfl_xor(s, m, 64);
    float rr = rsqrtf(s*(1.0f/128.0f) + 1.1920929e-07f);
    const float* ww = (g < 8) ? qw : kw;
    float sc = (g < 8) ? 0.125f : 1.0f;
    float qn0 = e0*rr*ww[l]*sc;
    float qn1 = e1*rr*ww[64+l]*sc;
    float p0 = rot[(size_t)n*128 + l], p1 = rot[(size_t)n*128 + 64 + l];
    float c0, s0, c1, s1;
    __sincosf(p0, &s0, &c0);
    __sincosf(p1, &s1, &c1);
    float o0 = qn0*c0 - qn1*s0;
    float o1 = qn1*c1 + qn0*s1;
    if (g < 8){
      Qf[((size_t)g*2048 + n)*128 + l]      = f2h(o0);
      Qf[((size_t)g*2048 + n)*128 + 64 + l] = f2h(o1);
    } else {
      int d0 = l, d1 = 64 + l;
      size_t ka0 = tbase + (size_t)((d0>>5)*2 + ((n>>4)&1))*512
                 + (size_t)(((d0>>3)&3)*16 + (n&15))*8 + (d0&7);
      size_t ka1 = tbase + (size_t)((d1>>5)*2 + ((n>>4)&1))*512
                 + (size_t)(((d1>>3)&3)*16 + (n&15))*8 + (d1&7);
      KVF[ka0] = f2h(o0);
      KVF[ka1] = f2h(o1);
    }
  } else {
    float v0 = h2f(row[1152 + l]);
    float v1 = h2f(row[1152 + 64 + l]);
    float v2 = h2f(row[1152 + 128 + l]);
    float s = v0*v0 + v1*v1 + v2*v2;
    #pragma unroll
    for (int m=1; m<64; m<<=1) s += __shfl_xor(s, m, 64);
    float rr = rsqrtf(s*(1.0f/192.0f) + 1.1920929e-07f);
    int lgv = (n>>3)&3, ev = n&7;
    size_t vbase = tbase + 4096;
    float vals[3] = {v0, v1, v2};
    #pragma unroll
    for (int j=0; j<3; ++j){
      int d = j*64 + l;
      KVF[vbase + (size_t)(d>>4)*512 + (size_t)(lgv*16 + (d&15))*8 + ev]
          = f2h(vals[j]*rr*vw[d]);
    }
  }
}

// ---- generic fragment-major fp16 GEMM, dbuf gload_lds, XCD-swizzled ----
__global__ __launch_bounds__(256,3) void k_gemm2(const u16* __restrict__ Afq,
    const u16* __restrict__ Bfq, void* __restrict__ Cv, int N, int nKt, int halfOut, int NX){
  __shared__ u16 lds[24576];
  int id = blockIdx.x;
  int per = gridDim.x >> 3;                  // gridDim.x % 8 == 0
  int id2 = (id & 7)*per + (id >> 3);
  int by = id2 / NX;
  int bx = id2 - by*NX;
  int t = threadIdx.x;
  int w = t>>6, lane = t&63, lg = lane>>4, lr = lane&15;
  int iw = w&1, jw = w>>1;
  int n0 = bx*64, m0 = by*128;
  const char* srcA = (const char*)(Afq + (size_t)by*nKt*8192);
  const char* srcB = (const char*)(Bfq + (size_t)bx*nKt*4096);
  int wb = w*1024 + lane*16;
  auto stage = [&](int kt, int cur){
    const char* ta = srcA + (size_t)kt*16384;
    const char* tb = srcB + (size_t)kt*8192;
    int ab = cur*12288;
    #pragma unroll
    for (int i=0; i<4; ++i)
      gload16(ta + i*4096 + wb, &lds[ab + ((i*4096 + w*1024)>>1)]);
    #pragma unroll
    for (int i=0; i<2; ++i)
      gload16(tb + i*4096 + wb, &lds[ab + 8192 + ((i*4096 + w*1024)>>1)]);
  };
  f32x4 acc[4][2] = {};
  stage(0, 0);
  __syncthreads();
  int cur = 0;
  for (int kt=0; kt<nKt; ++kt){
    if (kt+1 < nKt) stage(kt+1, cur^1);
    int ab = cur*12288;
    #pragma unroll
    for (int ks2=0; ks2<2; ++ks2){
      f16x8 ah[4], bh[2];
      #pragma unroll
      for (int m=0; m<4; ++m)
        ah[m] = *(const f16x8*)&lds[ab + (size_t)(ks2*8 + iw*4 + m)*512 + lane*8];
      #pragma unroll
      for (int n=0; n<2; ++n)
        bh[n] = *(const f16x8*)&lds[ab + 8192 + (size_t)(ks2*4 + jw*2 + n)*512 + lane*8];
      #pragma unroll
      for (int m=0; m<4; ++m)
        #pragma unroll
        for (int n=0; n<2; ++n)
          acc[m][n] = mfma16h(ah[m], bh[n], acc[m][n]);
    }
    __syncthreads();
    cur ^= 1;
  }
  #pragma unroll
  for (int m=0; m<4; ++m)
    #pragma unroll
    for (int n=0; n<2; ++n)
      #pragma unroll
      for (int r=0; r<4; ++r){
        int row = m0 + iw*64 + m*16 + lg*4 + r;
        int col = n0 + jw*32 + n*16 + lr;
        if (halfOut) ((u16*)Cv)[(size_t)row*N + col] = f2h(acc[m][n][r]);
        else         ((float*)Cv)[(size_t)row*N + col] = acc[m][n][r];
      }
}

// ------------- fused attention v6: fragment-major K/V, gload_lds staging, -------------
// (256,2): accO needs 96 VGPR -- (256,3) spills accumulators (R14 regression).
__global__ __launch_bounds__(256,2) void k_attn6(const u16* __restrict__ Qf,
  const u16* __restrict__ KVF, const u16* __restrict__ biash,
  u16* __restrict__ OP, float* __restrict__ SP){
  __shared__ u16 lds[24576];
  int t = threadIdx.x;
  int w = t>>6, lane = t&63, lg = lane>>4, lr = lane&15;
  int q0 = blockIdx.x*32;
  int h  = blockIdx.y*4 + w;
  int zi = blockIdx.z;
  f16x8 qf[2][4];
  #pragma unroll
  for (int qi=0; qi<2; ++qi){
    const u16* qb = Qf + ((size_t)h*2048 + q0 + qi*16 + lr)*128 + lg*8;
    #pragma unroll
    for (int ks=0; ks<4; ++ks) qf[qi][ks] = *(const f16x8*)(qb + ks*32);
  }
  const char* kvb = (const char*)KVF + (size_t)zi*16*20480;
  int wb = w*1024 + lane*16;
  auto stage = [&](int jt, int cur){
    const char* src = kvb + (size_t)jt*20480;
    gload16(src + wb,         &lds[cur*4096 + (w*1024>>1)]);
    gload16(src + 4096 + wb,  &lds[cur*4096 + 2048 + (w*1024>>1)]);
    gload16(src + 8192 + wb,  &lds[8192 + cur*6144 + (w*1024>>1)]);
    gload16(src + 12288 + wb, &lds[8192 + cur*6144 + 2048 + (w*1024>>1)]);
    gload16(src + 16384 + wb, &lds[8192 + cur*6144 + 4096 + (w*1024>>1)]);
  };
  float bCur[2][2], bNxt[2][2];
  auto loadBias = [&](int jt, float bb[2][2]){
    int jq = (zi*512 + jt*32)>>2;
    #pragma unroll
    for (int qi=0; qi<2; ++qi)
      #pragma unroll
      for (int kj=0; kj<2; ++kj)
        bb[qi][kj] = 0.4f*h2f(biash[((size_t)((q0>>2) + qi*4 + lg)*512 + jq + kj*4 + (lr>>2))*8 + h]);
  };
  stage(0, 0);
  loadBias(0, bCur);
  __syncthreads();
  f32x4 accO[2][12] = {};
  f32x4 accR[2] = {};
  f16x8 vone;
  #pragma unroll
  for (int e=0; e<8; ++e) vone[e] = (_Float16)1.0f;
  int psb = 20480 + w*1024;
  int po0 = lane*8;       po0 ^= ((po0>>6)&7)<<3;
  int po1 = 512 + lane*8; po1 ^= ((po1>>6)&7)<<3;
  int cur = 0;
  for (int jt=0; jt<16; ++jt){
    if (jt < 15){ stage(jt+1, cur^1); loadBias(jt+1, bNxt); }
    f32x4 accS[2][2] = {};
    #pragma unroll
    for (int ks=0; ks<4; ++ks){
      #pragma unroll
      for (int kj=0; kj<2; ++kj){
        f16x8 kb = *(const f16x8*)&lds[cur*4096 + (ks*2+kj)*512 + lane*8];
        accS[0][kj] = mfma16h(qf[0][ks], kb, accS[0][kj]);
        accS[1][kj] = mfma16h(qf[1][ks], kb, accS[1][kj]);
      }
    }
    #pragma unroll
    for (int qi=0; qi<2; ++qi)
      #pragma unroll
      for (int kj=0; kj<2; ++kj){
        float bv = bCur[qi][kj];
        #pragma unroll
        for (int r=0; r<4; ++r){
          float te = __expf(0.4f*accS[qi][kj][r] + bv);
          float ri; asm("v_rcp_f32 %0, %1" : "=v"(ri) : "v"(te + 1.0f));
          float p = __expf(-10.0f*ri);
          int o = qi*512 + ((kj*2 + (lr>>3))*16 + lg*4 + r)*8 + (lr&7);
          o ^= ((o>>6)&7)<<3;
          lds[psb + o] = f2h(p);
        }
      }
    f16x8 pa0 = *(const f16x8*)&lds[psb + po0];
    f16x8 pa1 = *(const f16x8*)&lds[psb + po1];
    #pragma unroll
    for (int df=0; df<12; ++df){
      f16x8 vb = *(const f16x8*)&lds[8192 + cur*6144 + df*512 + lane*8];
      accO[0][df] = mfma16h(pa0, vb, accO[0][df]);
      accO[1][df] = mfma16h(pa1, vb, accO[1][df]);
    }
    accR[0] = mfma16h(pa0, vone, accR[0]);
    accR[1] = mfma16h(pa1, vone, accR[1]);
    __syncthreads();
    cur ^= 1;
    #pragma unroll
    for (int qi=0; qi<2; ++qi){ bCur[qi][0] = bNxt[qi][0]; bCur[qi][1] = bNxt[qi][1]; }
  }
  #pragma unroll
  for (int qi=0; qi<2; ++qi){
    #pragma unroll
    for (int df=0; df<12; ++df)
      #pragma unroll
      for (int r=0; r<4; ++r){
        int q = q0 + qi*16 + lg*4 + r;
        OP[(((size_t)zi*8 + h)*2048 + q)*192 + df*16 + lr] = f2h(accO[qi][df][r]);
      }
    if (lr == 0)
      #pragma unroll
      for (int r=0; r<4; ++r)
        SP[((size_t)zi*8 + h)*2048 + q0 + qi*16 + lg*4 + r] = accR[qi][r];
  }
}

// ---- combine 4 z-partials, normalize, write fragment-major fp16 A-tiles for gemm2 ----
__global__ __launch_bounds__(256) void k_comb2(const u16* __restrict__ OP,
    const float* __restrict__ SP, u16* __restrict__ Ao2){
  int id = blockIdx.x*256 + threadIdx.x;    // 393216
  int hq = id / 24;
  int oct = id - hq*24;
  int d0 = oct*8;
  float inv = 1.0f / (SP[hq] + SP[16384+hq] + SP[32768+hq] + SP[49152+hq]);
  float o[8] = {0,0,0,0,0,0,0,0};
  #pragma unroll
  for (int z=0; z<4; ++z){
    uint4 v = *(const uint4*)&OP[((size_t)z*16384 + hq)*192 + d0];
    const u16* pv = (const u16*)&v;
    #pragma unroll
    for (int e=0; e<8; ++e) o[e] += h2f(pv[e]);
  }
  int h = hq >> 11, q = hq & 2047;
  int col = h*192 + d0;
  int kt = col>>6, ks2 = (col>>5)&1, lg = (col>>3)&3;
  int mt = q>>7, ms = (q>>4)&7, m16 = q&15;
  int lane = lg*16 + m16;
  u16 hh[8];
  #pragma unroll
  for (int e=0; e<8; ++e) hh[e] = f2h(o[e]*inv);
  size_t base = (size_t)(mt*24 + kt)*8192;
  *(uint4*)&Ao2[base + (size_t)(ks2*8 + ms)*512 + lane*8] = *(uint4*)hh;
}

extern "C" void kernel_launch(void* const* d_in, const int* in_sizes, int n_in,
                              void* d_out, int out_size, void* d_ws, size_t ws_size,
                              hipStream_t stream){
  (void)in_sizes; (void)n_in; (void)out_size; (void)ws_size;
  const float* x   = (const float*)d_in[0];
  const float* pwi = (const float*)d_in[1];
  const float* rot = (const float*)d_in[2];
  const float* Wq  = (const float*)d_in[3];
  const float* qw  = (const float*)d_in[4];
  const float* kw  = (const float*)d_in[5];
  const float* vw  = (const float*)d_in[6];
  const float* gm  = (const float*)d_in[7];
  const float* bt  = (const float*)d_in[8];
  const float* rvv = (const float*)d_in[9];
  const float* Wb  = (const float*)d_in[10];
  const float* Wo  = (const float*)d_in[11];
  float* out = (float*)d_out;
  char* ws = (char*)d_ws;
  size_t off = 0;
  auto alloc = [&](size_t bytes)->char*{
    char* p = ws + off; off = (off + bytes + 255) & ~(size_t)255; return p;
  };
  u16*   Axq = (u16*)alloc(16ull*16*8192*2);      // x frag-major fp16 (4 MB)
  u16*   Bq1 = (u16*)alloc(21ull*16*4096*2);      // Wqkv frag-major fp16 (2.75 MB)
  u16*   Bq2 = (u16*)alloc(16ull*24*4096*2);      // Wo frag-major fp16 (3.1 MB)
  u16*   Ao2 = (u16*)alloc(16ull*24*8192*2);      // attn-out frag-major fp16 (6.3 MB)
  u16*   qkvh = (u16*)alloc(2048ull*1344*2);      // qkv fp16 (5.5 MB)
  u16*   Qfb = (u16*)alloc(8ull*2048*128*2);
  u16*   KVF = (u16*)alloc(64ull*10240*2);
  u16*   biash = (u16*)alloc(8ull*512*512*2);     // bias f16 [pair][8] (4.2 MB)
  u16*   OP  = (u16*)alloc(4ull*8*2048*192*2);
  float* SP  = (float*)alloc(4ull*8*2048*4);

  k_bias5<<<2048, 256, 0, stream>>>(pwi, rvv, gm, bt, Wb, biash);
  k_pre<<<1744, 256, 0, stream>>>(x, Wq, Wo, Axq, Bq1, Bq2);
  k_gemm2<<<336, 256, 0, stream>>>(Axq, Bq1, qkvh, 1344, 16, 1, 21);
  k_norm<<<5120, 256, 0, stream>>>(qkvh, rot, qw, kw, vw, Qfb, KVF);
  k_attn6<<<dim3(64, 2, 4), 256, 0, stream>>>(Qfb, KVF, biash, OP, SP);
  k_comb2<<<1536, 256, 0, stream>>>(OP, SP, Ao2);
  k_gemm2<<<256, 256, 0, stream>>>(Ao2, Bq2, out, 1024, 24, 0, 16);
}

// Round 19
// 110.133 us; speedup vs baseline: 1.0972x; 1.0466x over previous
//
#include <hip/hip_runtime.h>
#include <math.h>

typedef unsigned short u16;
typedef __attribute__((ext_vector_type(4))) float f32x4;
typedef __attribute__((ext_vector_type(8))) short s16x8;
typedef __attribute__((ext_vector_type(8))) _Float16 f16x8;

__device__ __forceinline__ u16 f2bf(float f){
  unsigned u = __builtin_bit_cast(unsigned, f);
  u += 0x7fffu + ((u >> 16) & 1u);
  return (u16)(u >> 16);
}
__device__ __forceinline__ float bf2f(u16 h){
  unsigned u = ((unsigned)h) << 16;
  return __builtin_bit_cast(float, u);
}
__device__ __forceinline__ u16 f2h(float f){
  return __builtin_bit_cast(u16, (_Float16)f);
}
__device__ __forceinline__ float h2f(u16 h){
  return (float)__builtin_bit_cast(_Float16, h);
}
__device__ __forceinline__ f32x4 mfma16h(f16x8 a, f16x8 b, f32x4 c){
  return __builtin_amdgcn_mfma_f32_16x16x32_f16(a, b, c, 0, 0, 0);
}
__device__ __forceinline__ void gload16(const void* src, const u16* ldsbase){
  __builtin_amdgcn_global_load_lds(
      (const __attribute__((address_space(1))) void*)src,
      (__attribute__((address_space(3))) void*)ldsbase, 16, 0, 0);
}

// ---- fused preprocessing: x -> A-frags ; Wqkv -> B-frags ; Wo -> B-frags ----
__global__ __launch_bounds__(256) void k_pre(const float* __restrict__ x,
    const float* __restrict__ Wq, const float* __restrict__ Wo,
    u16* __restrict__ Afq, u16* __restrict__ Bq1, u16* __restrict__ Bq2){
  __shared__ float tile[64][65];
  int b = blockIdx.x, t = threadIdx.x;
  if (b < 1024){
    int id = b*256 + t;                       // 262144
    int row = id>>7, k0 = (id&127)*8;
    const float4* xp = (const float4*)(x + (size_t)row*1024 + k0);
    float4 v0 = xp[0], v1 = xp[1];
    float vv[8] = {v0.x,v0.y,v0.z,v0.w, v1.x,v1.y,v1.z,v1.w};
    u16 hh[8];
    #pragma unroll
    for (int e=0; e<8; ++e) hh[e] = f2h(vv[e]);
    int mt = row>>7, ms = (row>>4)&7, m16 = row&15;
    int kt = k0>>6, ks2 = (k0>>5)&1, lg = (k0>>3)&3;
    int lane = lg*16 + m16;
    size_t base = (size_t)(mt*16 + kt)*8192;
    *(uint4*)&Afq[base + (size_t)(ks2*8 + ms)*512 + lane*8] = *(uint4*)hh;
    return;
  }
  const float* in; u16* Bfq; int N, nKt, nt, kt;
  if (b < 1360){
    int bb = b - 1024; nt = bb % 21; kt = bb / 21;
    in = Wq; Bfq = Bq1; N = 1344; nKt = 16;
  } else {
    int bb = b - 1360; nt = bb % 16; kt = bb / 16;
    in = Wo; Bfq = Bq2; N = 1024; nKt = 24;
  }
  #pragma unroll
  for (int i=0; i<16; ++i){
    int idx = i*256 + t;
    int r = idx>>6, c = idx&63;
    tile[r][c] = in[(size_t)(kt*64 + r)*N + nt*64 + c];
  }
  __syncthreads();
  size_t base = (size_t)(nt*nKt + kt)*4096;
  #pragma unroll
  for (int j=0; j<2; ++j){
    int idx = j*256 + t;
    int np = idx>>3, ko = idx&7;
    u16 hh[8];
    #pragma unroll
    for (int e=0; e<8; ++e) hh[e] = f2h(tile[ko*8+e][np]);
    int ks2 = ko>>2, lg = ko&3, ns = np>>4, n16 = np&15;
    int lane = lg*16 + n16;
    *(uint4*)&Bfq[base + (size_t)(ks2*4 + ns)*512 + lane*8] = *(uint4*)hh;
  }
}

// ---- fused: gemm1 single-buffer 24KB (blocks [0,336)) + bias5 (blocks [336,2384)) ----
// Single-buffer gemm (R9: dbuf ~= single-buf) keeps LDS at 24 KB so BOTH parts get
// 6 blocks/CU at (256,6) -- fixes R15's 48KB/3-blocks bias starvation.
__global__ __launch_bounds__(256,6) void k_g1b2(const u16* __restrict__ Afq,
    const u16* __restrict__ Bq1, u16* __restrict__ qkvh,
    const float* __restrict__ pw, const float* __restrict__ rv,
    const float* __restrict__ gamma, const float* __restrict__ beta,
    const float* __restrict__ Wb, u16* __restrict__ biash){
  __shared__ u16 lds[12288];
  int b = blockIdx.x, t = threadIdx.x;
  int w = t>>6, lane = t&63, lg = lane>>4, lr = lane&15;
  if (b < 336){
    // ---------------- gemm1: qkv = x @ Wqkv (single-buffered) ----------------
    int id2 = (b & 7)*42 + (b >> 3);
    int by = id2 / 21, bx = id2 - by*21;
    int iw = w&1, jw = w>>1;
    int n0 = bx*64, m0 = by*128;
    const char* srcA = (const char*)(Afq + (size_t)by*16*8192);
    const char* srcB = (const char*)(Bq1 + (size_t)bx*16*4096);
    int wb = w*1024 + lane*16;
    f32x4 acc[4][2] = {};
    for (int kt=0; kt<16; ++kt){
      __syncthreads();                     // prev reads done
      const char* ta = srcA + (size_t)kt*16384;
      const char* tb = srcB + (size_t)kt*8192;
      #pragma unroll
      for (int i=0; i<4; ++i)
        gload16(ta + i*4096 + wb, &lds[(i*4096 + w*1024)>>1]);
      #pragma unroll
      for (int i=0; i<2; ++i)
        gload16(tb + i*4096 + wb, &lds[8192 + ((i*4096 + w*1024)>>1)]);
      __syncthreads();                     // vmcnt drained -> tile visible
      #pragma unroll
      for (int ks2=0; ks2<2; ++ks2){
        f16x8 ah[4], bh[2];
        #pragma unroll
        for (int m=0; m<4; ++m)
          ah[m] = *(const f16x8*)&lds[(size_t)(ks2*8 + iw*4 + m)*512 + lane*8];
        #pragma unroll
        for (int n=0; n<2; ++n)
          bh[n] = *(const f16x8*)&lds[8192 + (size_t)(ks2*4 + jw*2 + n)*512 + lane*8];
        #pragma unroll
        for (int m=0; m<4; ++m)
          #pragma unroll
          for (int n=0; n<2; ++n)
            acc[m][n] = mfma16h(ah[m], bh[n], acc[m][n]);
      }
    }
    #pragma unroll
    for (int m=0; m<4; ++m)
      #pragma unroll
      for (int n=0; n<2; ++n)
        #pragma unroll
        for (int r=0; r<4; ++r){
          int row = m0 + iw*64 + m*16 + lg*4 + r;
          int col = n0 + jw*32 + n*16 + lr;
          qkvh[(size_t)row*1344 + col] = f2h(acc[m][n][r]);
        }
    return;
  }
  // ---------------- bias part (tanh-gelu, fp16 single-MFMA) ----------------
  int bb = b - 336;
  float* As = (float*)lds;            // 128 f
  float* Bs = As + 128;               // 128 f
  u16* WbS = (u16*)(Bs + 128);        // 2048 u16
  if (t < 128){
    As[t] = 11.313708498984761f * rsqrtf(fmaxf(rv[t], 1e-5f)) * (gamma[t] + 1.0f);
    Bs[t] = beta[t];
  }
  {
    int ks = t>>6, lane2 = t&63, lg2 = lane2>>4, lr2 = lane2&15;
    #pragma unroll
    for (int e=0; e<8; ++e){
      float v = (lr2 < 8) ? Wb[(ks*32 + lg2*8 + e)*8 + lr2] : 0.0f;
      WbS[ks*512 + lane2*8 + e] = f2h(v);
    }
  }
  __syncthreads();
  #pragma unroll
  for (int it=0; it<2; ++it){
    int p0 = bb*128 + it*64 + w*16;
    const float* rowp = pw + (size_t)(p0 + lr)*128;
    f32x4 acc = {0.f,0.f,0.f,0.f};
    #pragma unroll
    for (int ks=0; ks<4; ++ks){
      int c = ks*32 + lg*8;
      float4 x0 = *(const float4*)(rowp + c);
      float4 x1 = *(const float4*)(rowp + c + 4);
      float4 a0 = *(const float4*)&As[c], a1 = *(const float4*)&As[c+4];
      float4 b0 = *(const float4*)&Bs[c], b1 = *(const float4*)&Bs[c+4];
      float xv[8] = {x0.x*a0.x+b0.x, x0.y*a0.y+b0.y, x0.z*a0.z+b0.z, x0.w*a0.w+b0.w,
                     x1.x*a1.x+b1.x, x1.y*a1.y+b1.y, x1.z*a1.z+b1.z, x1.w*a1.w+b1.w};
      f16x8 gh;
      #pragma unroll
      for (int e=0; e<8; ++e){
        float v = xv[e];
        float u2 = v*v;
        float arg = v*(1.5957691216f + 0.0713548162f*u2);   // 2u
        float te = __expf(arg);
        float ri; asm("v_rcp_f32 %0, %1" : "=v"(ri) : "v"(te + 1.0f));
        float ge = v - v*ri;
        gh[e] = (_Float16)ge;
      }
      f16x8 bh = *(const f16x8*)&WbS[ks*512 + lane*8];
      acc = mfma16h(gh, bh, acc);
    }
    if (lr < 8)
      #pragma unroll
      for (int r=0; r<4; ++r)
        biash[(size_t)(p0 + lg*4 + r)*8 + lr] = f2h(acc[r]);
  }
}

// ---- norm+rope only: one wave per (row n, group g): g=0..7 Q, g=8 K, g=9 V ----
__global__ __launch_bounds__(256) void k_norm(const u16* __restrict__ qkvh,
   const float* __restrict__ rot, const float* __restrict__ qw, const float* __restrict__ kw,
   const float* __restrict__ vw, u16* __restrict__ Qf, u16* __restrict__ KVF){
  int t = threadIdx.x;
  int w = t>>6, l = t&63;
  int task = blockIdx.x*4 + w;          // 20480 tasks
  int n = task/10, g = task - (task/10)*10;
  const u16* row = qkvh + (size_t)n*1344;
  size_t tbase = (size_t)(n>>5)*10240;
  if (g < 9){
    float e0 = h2f(row[g*128 + l]);
    float e1 = h2f(row[g*128 + 64 + l]);
    float s = e0*e0 + e1*e1;
    #pragma unroll
    for (int m=1; m<64; m<<=1) s += __shfl_xor(s, m, 64);
    float rr = rsqrtf(s*(1.0f/128.0f) + 1.1920929e-07f);
    const float* ww = (g < 8) ? qw : kw;
    float sc = (g < 8) ? 0.125f : 1.0f;
    float qn0 = e0*rr*ww[l]*sc;
    float qn1 = e1*rr*ww[64+l]*sc;
    float p0 = rot[(size_t)n*128 + l], p1 = rot[(size_t)n*128 + 64 + l];
    float c0, s0, c1, s1;
    __sincosf(p0, &s0, &c0);
    __sincosf(p1, &s1, &c1);
    float o0 = qn0*c0 - qn1*s0;
    float o1 = qn1*c1 + qn0*s1;
    if (g < 8){
      Qf[((size_t)g*2048 + n)*128 + l]      = f2h(o0);
      Qf[((size_t)g*2048 + n)*128 + 64 + l] = f2h(o1);
    } else {
      int d0 = l, d1 = 64 + l;
      size_t ka0 = tbase + (size_t)((d0>>5)*2 + ((n>>4)&1))*512
                 + (size_t)(((d0>>3)&3)*16 + (n&15))*8 + (d0&7);
      size_t ka1 = tbase + (size_t)((d1>>5)*2 + ((n>>4)&1))*512
                 + (size_t)(((d1>>3)&3)*16 + (n&15))*8 + (d1&7);
      KVF[ka0] = f2h(o0);
      KVF[ka1] = f2h(o1);
    }
  } else {
    float v0 = h2f(row[1152 + l]);
    float v1 = h2f(row[1152 + 64 + l]);
    float v2 = h2f(row[1152 + 128 + l]);
    float s = v0*v0 + v1*v1 + v2*v2;
    #pragma unroll
    for (int m=1; m<64; m<<=1) s += __shfl_xor(s, m, 64);
    float rr = rsqrtf(s*(1.0f/192.0f) + 1.1920929e-07f);
    int lgv = (n>>3)&3, ev = n&7;
    size_t vbase = tbase + 4096;
    float vals[3] = {v0, v1, v2};
    #pragma unroll
    for (int j=0; j<3; ++j){
      int d = j*64 + l;
      KVF[vbase + (size_t)(d>>4)*512 + (size_t)(lgv*16 + (d&15))*8 + ev]
          = f2h(vals[j]*rr*vw[d]);
    }
  }
}

// ---- generic fragment-major fp16 GEMM, dbuf gload_lds, XCD-swizzled (gemm2) ----
__global__ __launch_bounds__(256,3) void k_gemm2(const u16* __restrict__ Afq,
    const u16* __restrict__ Bfq, void* __restrict__ Cv, int N, int nKt, int halfOut, int NX){
  __shared__ u16 lds[24576];
  int id = blockIdx.x;
  int per = gridDim.x >> 3;                  // gridDim.x % 8 == 0
  int id2 = (id & 7)*per + (id >> 3);
  int by = id2 / NX;
  int bx = id2 - by*NX;
  int t = threadIdx.x;
  int w = t>>6, lane = t&63, lg = lane>>4, lr = lane&15;
  int iw = w&1, jw = w>>1;
  int n0 = bx*64, m0 = by*128;
  const char* srcA = (const char*)(Afq + (size_t)by*nKt*8192);
  const char* srcB = (const char*)(Bfq + (size_t)bx*nKt*4096);
  int wb = w*1024 + lane*16;
  auto stage = [&](int kt, int cur){
    const char* ta = srcA + (size_t)kt*16384;
    const char* tb = srcB + (size_t)kt*8192;
    int ab = cur*12288;
    #pragma unroll
    for (int i=0; i<4; ++i)
      gload16(ta + i*4096 + wb, &lds[ab + ((i*4096 + w*1024)>>1)]);
    #pragma unroll
    for (int i=0; i<2; ++i)
      gload16(tb + i*4096 + wb, &lds[ab + 8192 + ((i*4096 + w*1024)>>1)]);
  };
  f32x4 acc[4][2] = {};
  stage(0, 0);
  __syncthreads();
  int cur = 0;
  for (int kt=0; kt<nKt; ++kt){
    if (kt+1 < nKt) stage(kt+1, cur^1);
    int ab = cur*12288;
    #pragma unroll
    for (int ks2=0; ks2<2; ++ks2){
      f16x8 ah[4], bh[2];
      #pragma unroll
      for (int m=0; m<4; ++m)
        ah[m] = *(const f16x8*)&lds[ab + (size_t)(ks2*8 + iw*4 + m)*512 + lane*8];
      #pragma unroll
      for (int n=0; n<2; ++n)
        bh[n] = *(const f16x8*)&lds[ab + 8192 + (size_t)(ks2*4 + jw*2 + n)*512 + lane*8];
      #pragma unroll
      for (int m=0; m<4; ++m)
        #pragma unroll
        for (int n=0; n<2; ++n)
          acc[m][n] = mfma16h(ah[m], bh[n], acc[m][n]);
    }
    __syncthreads();
    cur ^= 1;
  }
  #pragma unroll
  for (int m=0; m<4; ++m)
    #pragma unroll
    for (int n=0; n<2; ++n)
      #pragma unroll
      for (int r=0; r<4; ++r){
        int row = m0 + iw*64 + m*16 + lg*4 + r;
        int col = n0 + jw*32 + n*16 + lr;
        if (halfOut) ((u16*)Cv)[(size_t)row*N + col] = f2h(acc[m][n][r]);
        else         ((float*)Cv)[(size_t)row*N + col] = acc[m][n][r];
      }
}

// ------------- fused attention v6: fragment-major K/V, gload_lds staging, -------------
// (256,2): accO needs 96 VGPR -- (256,3) spills accumulators (R14 regression).
__global__ __launch_bounds__(256,2) void k_attn6(const u16* __restrict__ Qf,
  const u16* __restrict__ KVF, const u16* __restrict__ biash,
  u16* __restrict__ OP, float* __restrict__ SP){
  __shared__ u16 lds[24576];
  int t = threadIdx.x;
  int w = t>>6, lane = t&63, lg = lane>>4, lr = lane&15;
  int q0 = blockIdx.x*32;
  int h  = blockIdx.y*4 + w;
  int zi = blockIdx.z;
  f16x8 qf[2][4];
  #pragma unroll
  for (int qi=0; qi<2; ++qi){
    const u16* qb = Qf + ((size_t)h*2048 + q0 + qi*16 + lr)*128 + lg*8;
    #pragma unroll
    for (int ks=0; ks<4; ++ks) qf[qi][ks] = *(const f16x8*)(qb + ks*32);
  }
  const char* kvb = (const char*)KVF + (size_t)zi*16*20480;
  int wb = w*1024 + lane*16;
  auto stage = [&](int jt, int cur){
    const char* src = kvb + (size_t)jt*20480;
    gload16(src + wb,         &lds[cur*4096 + (w*1024>>1)]);
    gload16(src + 4096 + wb,  &lds[cur*4096 + 2048 + (w*1024>>1)]);
    gload16(src + 8192 + wb,  &lds[8192 + cur*6144 + (w*1024>>1)]);
    gload16(src + 12288 + wb, &lds[8192 + cur*6144 + 2048 + (w*1024>>1)]);
    gload16(src + 16384 + wb, &lds[8192 + cur*6144 + 4096 + (w*1024>>1)]);
  };
  float bCur[2][2], bNxt[2][2];
  auto loadBias = [&](int jt, float bb[2][2]){
    int jq = (zi*512 + jt*32)>>2;
    #pragma unroll
    for (int qi=0; qi<2; ++qi)
      #pragma unroll
      for (int kj=0; kj<2; ++kj)
        bb[qi][kj] = 0.4f*h2f(biash[((size_t)((q0>>2) + qi*4 + lg)*512 + jq + kj*4 + (lr>>2))*8 + h]);
  };
  stage(0, 0);
  loadBias(0, bCur);
  __syncthreads();
  f32x4 accO[2][12] = {};
  f32x4 accR[2] = {};
  f16x8 vone;
  #pragma unroll
  for (int e=0; e<8; ++e) vone[e] = (_Float16)1.0f;
  int psb = 20480 + w*1024;
  int po0 = lane*8;       po0 ^= ((po0>>6)&7)<<3;
  int po1 = 512 + lane*8; po1 ^= ((po1>>6)&7)<<3;
  int cur = 0;
  for (int jt=0; jt<16; ++jt){
    if (jt < 15){ stage(jt+1, cur^1); loadBias(jt+1, bNxt); }
    f32x4 accS[2][2] = {};
    #pragma unroll
    for (int ks=0; ks<4; ++ks){
      #pragma unroll
      for (int kj=0; kj<2; ++kj){
        f16x8 kb = *(const f16x8*)&lds[cur*4096 + (ks*2+kj)*512 + lane*8];
        accS[0][kj] = mfma16h(qf[0][ks], kb, accS[0][kj]);
        accS[1][kj] = mfma16h(qf[1][ks], kb, accS[1][kj]);
      }
    }
    #pragma unroll
    for (int qi=0; qi<2; ++qi)
      #pragma unroll
      for (int kj=0; kj<2; ++kj){
        float bv = bCur[qi][kj];
        #pragma unroll
        for (int r=0; r<4; ++r){
          float te = __expf(0.4f*accS[qi][kj][r] + bv);
          float ri; asm("v_rcp_f32 %0, %1" : "=v"(ri) : "v"(te + 1.0f));
          float p = __expf(-10.0f*ri);
          int o = qi*512 + ((kj*2 + (lr>>3))*16 + lg*4 + r)*8 + (lr&7);
          o ^= ((o>>6)&7)<<3;
          lds[psb + o] = f2h(p);
        }
      }
    f16x8 pa0 = *(const f16x8*)&lds[psb + po0];
    f16x8 pa1 = *(const f16x8*)&lds[psb + po1];
    #pragma unroll
    for (int df=0; df<12; ++df){
      f16x8 vb = *(const f16x8*)&lds[8192 + cur*6144 + df*512 + lane*8];
      accO[0][df] = mfma16h(pa0, vb, accO[0][df]);
      accO[1][df] = mfma16h(pa1, vb, accO[1][df]);
    }
    accR[0] = mfma16h(pa0, vone, accR[0]);
    accR[1] = mfma16h(pa1, vone, accR[1]);
    __syncthreads();
    cur ^= 1;
    #pragma unroll
    for (int qi=0; qi<2; ++qi){ bCur[qi][0] = bNxt[qi][0]; bCur[qi][1] = bNxt[qi][1]; }
  }
  #pragma unroll
  for (int qi=0; qi<2; ++qi){
    #pragma unroll
    for (int df=0; df<12; ++df)
      #pragma unroll
      for (int r=0; r<4; ++r){
        int q = q0 + qi*16 + lg*4 + r;
        OP[(((size_t)zi*8 + h)*2048 + q)*192 + df*16 + lr] = f2h(accO[qi][df][r]);
      }
    if (lr == 0)
      #pragma unroll
      for (int r=0; r<4; ++r)
        SP[((size_t)zi*8 + h)*2048 + q0 + qi*16 + lg*4 + r] = accR[qi][r];
  }
}

// ---- combine 4 z-partials, normalize, write fragment-major fp16 A-tiles for gemm2 ----
__global__ __launch_bounds__(256) void k_comb2(const u16* __restrict__ OP,
    const float* __restrict__ SP, u16* __restrict__ Ao2){
  int id = blockIdx.x*256 + threadIdx.x;    // 393216
  int hq = id / 24;
  int oct = id - hq*24;
  int d0 = oct*8;
  float inv = 1.0f / (SP[hq] + SP[16384+hq] + SP[32768+hq] + SP[49152+hq]);
  float o[8] = {0,0,0,0,0,0,0,0};
  #pragma unroll
  for (int z=0; z<4; ++z){
    uint4 v = *(const uint4*)&OP[((size_t)z*16384 + hq)*192 + d0];
    const u16* pv = (const u16*)&v;
    #pragma unroll
    for (int e=0; e<8; ++e) o[e] += h2f(pv[e]);
  }
  int h = hq >> 11, q = hq & 2047;
  int col = h*192 + d0;
  int kt = col>>6, ks2 = (col>>5)&1, lg = (col>>3)&3;
  int mt = q>>7, ms = (q>>4)&7, m16 = q&15;
  int lane = lg*16 + m16;
  u16 hh[8];
  #pragma unroll
  for (int e=0; e<8; ++e) hh[e] = f2h(o[e]*inv);
  size_t base = (size_t)(mt*24 + kt)*8192;
  *(uint4*)&Ao2[base + (size_t)(ks2*8 + ms)*512 + lane*8] = *(uint4*)hh;
}

extern "C" void kernel_launch(void* const* d_in, const int* in_sizes, int n_in,
                              void* d_out, int out_size, void* d_ws, size_t ws_size,
                              hipStream_t stream){
  (void)in_sizes; (void)n_in; (void)out_size; (void)ws_size;
  const float* x   = (const float*)d_in[0];
  const float* pwi = (const float*)d_in[1];
  const float* rot = (const float*)d_in[2];
  const float* Wq  = (const float*)d_in[3];
  const float* qw  = (const float*)d_in[4];
  const float* kw  = (const float*)d_in[5];
  const float* vw  = (const float*)d_in[6];
  const float* gm  = (const float*)d_in[7];
  const float* bt  = (const float*)d_in[8];
  const float* rvv = (const float*)d_in[9];
  const float* Wb  = (const float*)d_in[10];
  const float* Wo  = (const float*)d_in[11];
  float* out = (float*)d_out;
  char* ws = (char*)d_ws;
  size_t off = 0;
  auto alloc = [&](size_t bytes)->char*{
    char* p = ws + off; off = (off + bytes + 255) & ~(size_t)255; return p;
  };
  u16*   Axq = (u16*)alloc(16ull*16*8192*2);      // x frag-major fp16 (4 MB)
  u16*   Bq1 = (u16*)alloc(21ull*16*4096*2);      // Wqkv frag-major fp16 (2.75 MB)
  u16*   Bq2 = (u16*)alloc(16ull*24*4096*2);      // Wo frag-major fp16 (3.1 MB)
  u16*   Ao2 = (u16*)alloc(16ull*24*8192*2);      // attn-out frag-major fp16 (6.3 MB)
  u16*   qkvh = (u16*)alloc(2048ull*1344*2);      // qkv fp16 (5.5 MB)
  u16*   Qfb = (u16*)alloc(8ull*2048*128*2);
  u16*   KVF = (u16*)alloc(64ull*10240*2);
  u16*   biash = (u16*)alloc(8ull*512*512*2);     // bias f16 [pair][8] (4.2 MB)
  u16*   OP  = (u16*)alloc(4ull*8*2048*192*2);
  float* SP  = (float*)alloc(4ull*8*2048*4);

  k_pre<<<1744, 256, 0, stream>>>(x, Wq, Wo, Axq, Bq1, Bq2);
  k_g1b2<<<2384, 256, 0, stream>>>(Axq, Bq1, qkvh, pwi, rvv, gm, bt, Wb, biash);
  k_norm<<<5120, 256, 0, stream>>>(qkvh, rot, qw, kw, vw, Qfb, KVF);
  k_attn6<<<dim3(64, 2, 4), 256, 0, stream>>>(Qfb, KVF, biash, OP, SP);
  k_comb2<<<1536, 256, 0, stream>>>(OP, SP, Ao2);
  k_gemm2<<<256, 256, 0, stream>>>(Ao2, Bq2, out, 1024, 24, 0, 16);
}

// Round 20
// 107.172 us; speedup vs baseline: 1.1275x; 1.0276x over previous
//
#include <hip/hip_runtime.h>
#include <math.h>

typedef unsigned short u16;
typedef __attribute__((ext_vector_type(4))) float f32x4;
typedef __attribute__((ext_vector_type(8))) short s16x8;
typedef __attribute__((ext_vector_type(8))) _Float16 f16x8;

__device__ __forceinline__ u16 f2bf(float f){
  unsigned u = __builtin_bit_cast(unsigned, f);
  u += 0x7fffu + ((u >> 16) & 1u);
  return (u16)(u >> 16);
}
__device__ __forceinline__ float bf2f(u16 h){
  unsigned u = ((unsigned)h) << 16;
  return __builtin_bit_cast(float, u);
}
__device__ __forceinline__ u16 f2h(float f){
  return __builtin_bit_cast(u16, (_Float16)f);
}
__device__ __forceinline__ float h2f(u16 h){
  return (float)__builtin_bit_cast(_Float16, h);
}
__device__ __forceinline__ f32x4 mfma16h(f16x8 a, f16x8 b, f32x4 c){
  return __builtin_amdgcn_mfma_f32_16x16x32_f16(a, b, c, 0, 0, 0);
}
__device__ __forceinline__ void gload16(const void* src, const u16* ldsbase){
  __builtin_amdgcn_global_load_lds(
      (const __attribute__((address_space(1))) void*)src,
      (__attribute__((address_space(3))) void*)ldsbase, 16, 0, 0);
}

// ---- fused preprocessing: x -> A-frags ; Wqkv -> B-frags ; Wo -> B-frags ----
__global__ __launch_bounds__(256) void k_pre(const float* __restrict__ x,
    const float* __restrict__ Wq, const float* __restrict__ Wo,
    u16* __restrict__ Afq, u16* __restrict__ Bq1, u16* __restrict__ Bq2){
  __shared__ float tile[64][65];
  int b = blockIdx.x, t = threadIdx.x;
  if (b < 1024){
    int id = b*256 + t;                       // 262144
    int row = id>>7, k0 = (id&127)*8;
    const float4* xp = (const float4*)(x + (size_t)row*1024 + k0);
    float4 v0 = xp[0], v1 = xp[1];
    float vv[8] = {v0.x,v0.y,v0.z,v0.w, v1.x,v1.y,v1.z,v1.w};
    u16 hh[8];
    #pragma unroll
    for (int e=0; e<8; ++e) hh[e] = f2h(vv[e]);
    int mt = row>>7, ms = (row>>4)&7, m16 = row&15;
    int kt = k0>>6, ks2 = (k0>>5)&1, lg = (k0>>3)&3;
    int lane = lg*16 + m16;
    size_t base = (size_t)(mt*16 + kt)*8192;
    *(uint4*)&Afq[base + (size_t)(ks2*8 + ms)*512 + lane*8] = *(uint4*)hh;
    return;
  }
  const float* in; u16* Bfq; int N, nKt, nt, kt;
  if (b < 1360){
    int bb = b - 1024; nt = bb % 21; kt = bb / 21;
    in = Wq; Bfq = Bq1; N = 1344; nKt = 16;
  } else {
    int bb = b - 1360; nt = bb % 16; kt = bb / 16;
    in = Wo; Bfq = Bq2; N = 1024; nKt = 24;
  }
  #pragma unroll
  for (int i=0; i<16; ++i){
    int idx = i*256 + t;
    int r = idx>>6, c = idx&63;
    tile[r][c] = in[(size_t)(kt*64 + r)*N + nt*64 + c];
  }
  __syncthreads();
  size_t base = (size_t)(nt*nKt + kt)*4096;
  #pragma unroll
  for (int j=0; j<2; ++j){
    int idx = j*256 + t;
    int np = idx>>3, ko = idx&7;
    u16 hh[8];
    #pragma unroll
    for (int e=0; e<8; ++e) hh[e] = f2h(tile[ko*8+e][np]);
    int ks2 = ko>>2, lg = ko&3, ns = np>>4, n16 = np&15;
    int lane = lg*16 + n16;
    *(uint4*)&Bfq[base + (size_t)(ks2*4 + ns)*512 + lane*8] = *(uint4*)hh;
  }
}

// ---- fused: gemm1 single-buffer 24KB (blocks [0,336)) + bias (blocks [336,2384)) ----
__global__ __launch_bounds__(256,6) void k_g1b2(const u16* __restrict__ Afq,
    const u16* __restrict__ Bq1, u16* __restrict__ qkvh,
    const float* __restrict__ pw, const float* __restrict__ rv,
    const float* __restrict__ gamma, const float* __restrict__ beta,
    const float* __restrict__ Wb, u16* __restrict__ biash){
  __shared__ u16 lds[12288];
  int b = blockIdx.x, t = threadIdx.x;
  int w = t>>6, lane = t&63, lg = lane>>4, lr = lane&15;
  if (b < 336){
    int id2 = (b & 7)*42 + (b >> 3);
    int by = id2 / 21, bx = id2 - by*21;
    int iw = w&1, jw = w>>1;
    int n0 = bx*64, m0 = by*128;
    const char* srcA = (const char*)(Afq + (size_t)by*16*8192);
    const char* srcB = (const char*)(Bq1 + (size_t)bx*16*4096);
    int wb = w*1024 + lane*16;
    f32x4 acc[4][2] = {};
    for (int kt=0; kt<16; ++kt){
      __syncthreads();
      const char* ta = srcA + (size_t)kt*16384;
      const char* tb = srcB + (size_t)kt*8192;
      #pragma unroll
      for (int i=0; i<4; ++i)
        gload16(ta + i*4096 + wb, &lds[(i*4096 + w*1024)>>1]);
      #pragma unroll
      for (int i=0; i<2; ++i)
        gload16(tb + i*4096 + wb, &lds[8192 + ((i*4096 + w*1024)>>1)]);
      __syncthreads();
      #pragma unroll
      for (int ks2=0; ks2<2; ++ks2){
        f16x8 ah[4], bh[2];
        #pragma unroll
        for (int m=0; m<4; ++m)
          ah[m] = *(const f16x8*)&lds[(size_t)(ks2*8 + iw*4 + m)*512 + lane*8];
        #pragma unroll
        for (int n=0; n<2; ++n)
          bh[n] = *(const f16x8*)&lds[8192 + (size_t)(ks2*4 + jw*2 + n)*512 + lane*8];
        #pragma unroll
        for (int m=0; m<4; ++m)
          #pragma unroll
          for (int n=0; n<2; ++n)
            acc[m][n] = mfma16h(ah[m], bh[n], acc[m][n]);
      }
    }
    #pragma unroll
    for (int m=0; m<4; ++m)
      #pragma unroll
      for (int n=0; n<2; ++n)
        #pragma unroll
        for (int r=0; r<4; ++r){
          int row = m0 + iw*64 + m*16 + lg*4 + r;
          int col = n0 + jw*32 + n*16 + lr;
          qkvh[(size_t)row*1344 + col] = f2h(acc[m][n][r]);
        }
    return;
  }
  int bb = b - 336;
  float* As = (float*)lds;
  float* Bs = As + 128;
  u16* WbS = (u16*)(Bs + 128);
  if (t < 128){
    As[t] = 11.313708498984761f * rsqrtf(fmaxf(rv[t], 1e-5f)) * (gamma[t] + 1.0f);
    Bs[t] = beta[t];
  }
  {
    int ks = t>>6, lane2 = t&63, lg2 = lane2>>4, lr2 = lane2&15;
    #pragma unroll
    for (int e=0; e<8; ++e){
      float v = (lr2 < 8) ? Wb[(ks*32 + lg2*8 + e)*8 + lr2] : 0.0f;
      WbS[ks*512 + lane2*8 + e] = f2h(v);
    }
  }
  __syncthreads();
  #pragma unroll
  for (int it=0; it<2; ++it){
    int p0 = bb*128 + it*64 + w*16;
    const float* rowp = pw + (size_t)(p0 + lr)*128;
    f32x4 acc = {0.f,0.f,0.f,0.f};
    #pragma unroll
    for (int ks=0; ks<4; ++ks){
      int c = ks*32 + lg*8;
      float4 x0 = *(const float4*)(rowp + c);
      float4 x1 = *(const float4*)(rowp + c + 4);
      float4 a0 = *(const float4*)&As[c], a1 = *(const float4*)&As[c+4];
      float4 b0 = *(const float4*)&Bs[c], b1 = *(const float4*)&Bs[c+4];
      float xv[8] = {x0.x*a0.x+b0.x, x0.y*a0.y+b0.y, x0.z*a0.z+b0.z, x0.w*a0.w+b0.w,
                     x1.x*a1.x+b1.x, x1.y*a1.y+b1.y, x1.z*a1.z+b1.z, x1.w*a1.w+b1.w};
      f16x8 gh;
      #pragma unroll
      for (int e=0; e<8; ++e){
        float v = xv[e];
        float u2 = v*v;
        float arg = v*(1.5957691216f + 0.0713548162f*u2);
        float te = __expf(arg);
        float ri; asm("v_rcp_f32 %0, %1" : "=v"(ri) : "v"(te + 1.0f));
        float ge = v - v*ri;
        gh[e] = (_Float16)ge;
      }
      f16x8 bh = *(const f16x8*)&WbS[ks*512 + lane*8];
      acc = mfma16h(gh, bh, acc);
    }
    if (lr < 8)
      #pragma unroll
      for (int r=0; r<4; ++r)
        biash[(size_t)(p0 + lg*4 + r)*8 + lr] = f2h(acc[r]);
  }
}

// ---- norm+rope only ----
__global__ __launch_bounds__(256) void k_norm(const u16* __restrict__ qkvh,
   const float* __restrict__ rot, const float* __restrict__ qw, const float* __restrict__ kw,
   const float* __restrict__ vw, u16* __restrict__ Qf, u16* __restrict__ KVF){
  int t = threadIdx.x;
  int w = t>>6, l = t&63;
  int task = blockIdx.x*4 + w;          // 20480 tasks
  int n = task/10, g = task - (task/10)*10;
  const u16* row = qkvh + (size_t)n*1344;
  size_t tbase = (size_t)(n>>5)*10240;
  if (g < 9){
    float e0 = h2f(row[g*128 + l]);
    float e1 = h2f(row[g*128 + 64 + l]);
    float s = e0*e0 + e1*e1;
    #pragma unroll
    for (int m=1; m<64; m<<=1) s += __shfl_xor(s, m, 64);
    float rr = rsqrtf(s*(1.0f/128.0f) + 1.1920929e-07f);
    const float* ww = (g < 8) ? qw : kw;
    float sc = (g < 8) ? 0.125f : 1.0f;
    float qn0 = e0*rr*ww[l]*sc;
    float qn1 = e1*rr*ww[64+l]*sc;
    float p0 = rot[(size_t)n*128 + l], p1 = rot[(size_t)n*128 + 64 + l];
    float c0, s0, c1, s1;
    __sincosf(p0, &s0, &c0);
    __sincosf(p1, &s1, &c1);
    float o0 = qn0*c0 - qn1*s0;
    float o1 = qn1*c1 + qn0*s1;
    if (g < 8){
      Qf[((size_t)g*2048 + n)*128 + l]      = f2h(o0);
      Qf[((size_t)g*2048 + n)*128 + 64 + l] = f2h(o1);
    } else {
      int d0 = l, d1 = 64 + l;
      size_t ka0 = tbase + (size_t)((d0>>5)*2 + ((n>>4)&1))*512
                 + (size_t)(((d0>>3)&3)*16 + (n&15))*8 + (d0&7);
      size_t ka1 = tbase + (size_t)((d1>>5)*2 + ((n>>4)&1))*512
                 + (size_t)(((d1>>3)&3)*16 + (n&15))*8 + (d1&7);
      KVF[ka0] = f2h(o0);
      KVF[ka1] = f2h(o1);
    }
  } else {
    float v0 = h2f(row[1152 + l]);
    float v1 = h2f(row[1152 + 64 + l]);
    float v2 = h2f(row[1152 + 128 + l]);
    float s = v0*v0 + v1*v1 + v2*v2;
    #pragma unroll
    for (int m=1; m<64; m<<=1) s += __shfl_xor(s, m, 64);
    float rr = rsqrtf(s*(1.0f/192.0f) + 1.1920929e-07f);
    int lgv = (n>>3)&3, ev = n&7;
    size_t vbase = tbase + 4096;
    float vals[3] = {v0, v1, v2};
    #pragma unroll
    for (int j=0; j<3; ++j){
      int d = j*64 + l;
      KVF[vbase + (size_t)(d>>4)*512 + (size_t)(lgv*16 + (d&15))*8 + ev]
          = f2h(vals[j]*rr*vw[d]);
    }
  }
}

// ---- output GEMM: 64x64 tiles, dbuf gload_lds, 512 blocks = 2/CU ----
// A-tiles are 64-row fragment-major (4096 u16): [ks2*4+ms][lane][8], ms 0..3.
__global__ __launch_bounds__(256,4) void k_gemm3(const u16* __restrict__ Afq,
    const u16* __restrict__ Bfq, float* __restrict__ C, int N, int nKt, int NX){
  __shared__ u16 lds[16384];
  int id = blockIdx.x;
  int per = gridDim.x >> 3;
  int id2 = (id & 7)*per + (id >> 3);
  int by = id2 / NX;
  int bx = id2 - by*NX;
  int t = threadIdx.x;
  int w = t>>6, lane = t&63, lg = lane>>4, lr = lane&15;
  int iw = w&1, jw = w>>1;
  int n0 = bx*64, m0 = by*64;
  const char* srcA = (const char*)(Afq + (size_t)by*nKt*4096);
  const char* srcB = (const char*)(Bfq + (size_t)bx*nKt*4096);
  int wb = w*1024 + lane*16;
  auto stage = [&](int kt, int cur){
    const char* ta = srcA + (size_t)kt*8192;
    const char* tb = srcB + (size_t)kt*8192;
    int ab = cur*8192;
    #pragma unroll
    for (int i=0; i<2; ++i)
      gload16(ta + i*4096 + wb, &lds[ab + ((i*4096 + w*1024)>>1)]);
    #pragma unroll
    for (int i=0; i<2; ++i)
      gload16(tb + i*4096 + wb, &lds[ab + 4096 + ((i*4096 + w*1024)>>1)]);
  };
  f32x4 acc[2][2] = {};
  stage(0, 0);
  __syncthreads();
  int cur = 0;
  for (int kt=0; kt<nKt; ++kt){
    if (kt+1 < nKt) stage(kt+1, cur^1);
    int ab = cur*8192;
    #pragma unroll
    for (int ks2=0; ks2<2; ++ks2){
      f16x8 ah[2], bh[2];
      #pragma unroll
      for (int m=0; m<2; ++m)
        ah[m] = *(const f16x8*)&lds[ab + (size_t)(ks2*4 + iw*2 + m)*512 + lane*8];
      #pragma unroll
      for (int n=0; n<2; ++n)
        bh[n] = *(const f16x8*)&lds[ab + 4096 + (size_t)(ks2*4 + jw*2 + n)*512 + lane*8];
      #pragma unroll
      for (int m=0; m<2; ++m)
        #pragma unroll
        for (int n=0; n<2; ++n)
          acc[m][n] = mfma16h(ah[m], bh[n], acc[m][n]);
    }
    __syncthreads();
    cur ^= 1;
  }
  #pragma unroll
  for (int m=0; m<2; ++m)
    #pragma unroll
    for (int n=0; n<2; ++n)
      #pragma unroll
      for (int r=0; r<4; ++r){
        int row = m0 + iw*32 + m*16 + lg*4 + r;
        int col = n0 + jw*32 + n*16 + lr;
        C[(size_t)row*N + col] = acc[m][n][r];
      }
}

// ------------- fused attention v6 (unchanged from R19) -------------
__global__ __launch_bounds__(256,2) void k_attn6(const u16* __restrict__ Qf,
  const u16* __restrict__ KVF, const u16* __restrict__ biash,
  u16* __restrict__ OP, float* __restrict__ SP){
  __shared__ u16 lds[24576];
  int t = threadIdx.x;
  int w = t>>6, lane = t&63, lg = lane>>4, lr = lane&15;
  int q0 = blockIdx.x*32;
  int h  = blockIdx.y*4 + w;
  int zi = blockIdx.z;
  f16x8 qf[2][4];
  #pragma unroll
  for (int qi=0; qi<2; ++qi){
    const u16* qb = Qf + ((size_t)h*2048 + q0 + qi*16 + lr)*128 + lg*8;
    #pragma unroll
    for (int ks=0; ks<4; ++ks) qf[qi][ks] = *(const f16x8*)(qb + ks*32);
  }
  const char* kvb = (const char*)KVF + (size_t)zi*16*20480;
  int wb = w*1024 + lane*16;
  auto stage = [&](int jt, int cur){
    const char* src = kvb + (size_t)jt*20480;
    gload16(src + wb,         &lds[cur*4096 + (w*1024>>1)]);
    gload16(src + 4096 + wb,  &lds[cur*4096 + 2048 + (w*1024>>1)]);
    gload16(src + 8192 + wb,  &lds[8192 + cur*6144 + (w*1024>>1)]);
    gload16(src + 12288 + wb, &lds[8192 + cur*6144 + 2048 + (w*1024>>1)]);
    gload16(src + 16384 + wb, &lds[8192 + cur*6144 + 4096 + (w*1024>>1)]);
  };
  float bCur[2][2], bNxt[2][2];
  auto loadBias = [&](int jt, float bb[2][2]){
    int jq = (zi*512 + jt*32)>>2;
    #pragma unroll
    for (int qi=0; qi<2; ++qi)
      #pragma unroll
      for (int kj=0; kj<2; ++kj)
        bb[qi][kj] = 0.4f*h2f(biash[((size_t)((q0>>2) + qi*4 + lg)*512 + jq + kj*4 + (lr>>2))*8 + h]);
  };
  stage(0, 0);
  loadBias(0, bCur);
  __syncthreads();
  f32x4 accO[2][12] = {};
  f32x4 accR[2] = {};
  f16x8 vone;
  #pragma unroll
  for (int e=0; e<8; ++e) vone[e] = (_Float16)1.0f;
  int psb = 20480 + w*1024;
  int po0 = lane*8;       po0 ^= ((po0>>6)&7)<<3;
  int po1 = 512 + lane*8; po1 ^= ((po1>>6)&7)<<3;
  int cur = 0;
  for (int jt=0; jt<16; ++jt){
    if (jt < 15){ stage(jt+1, cur^1); loadBias(jt+1, bNxt); }
    f32x4 accS[2][2] = {};
    #pragma unroll
    for (int ks=0; ks<4; ++ks){
      #pragma unroll
      for (int kj=0; kj<2; ++kj){
        f16x8 kb = *(const f16x8*)&lds[cur*4096 + (ks*2+kj)*512 + lane*8];
        accS[0][kj] = mfma16h(qf[0][ks], kb, accS[0][kj]);
        accS[1][kj] = mfma16h(qf[1][ks], kb, accS[1][kj]);
      }
    }
    #pragma unroll
    for (int qi=0; qi<2; ++qi)
      #pragma unroll
      for (int kj=0; kj<2; ++kj){
        float bv = bCur[qi][kj];
        #pragma unroll
        for (int r=0; r<4; ++r){
          float te = __expf(0.4f*accS[qi][kj][r] + bv);
          float ri; asm("v_rcp_f32 %0, %1" : "=v"(ri) : "v"(te + 1.0f));
          float p = __expf(-10.0f*ri);
          int o = qi*512 + ((kj*2 + (lr>>3))*16 + lg*4 + r)*8 + (lr&7);
          o ^= ((o>>6)&7)<<3;
          lds[psb + o] = f2h(p);
        }
      }
    f16x8 pa0 = *(const f16x8*)&lds[psb + po0];
    f16x8 pa1 = *(const f16x8*)&lds[psb + po1];
    #pragma unroll
    for (int df=0; df<12; ++df){
      f16x8 vb = *(const f16x8*)&lds[8192 + cur*6144 + df*512 + lane*8];
      accO[0][df] = mfma16h(pa0, vb, accO[0][df]);
      accO[1][df] = mfma16h(pa1, vb, accO[1][df]);
    }
    accR[0] = mfma16h(pa0, vone, accR[0]);
    accR[1] = mfma16h(pa1, vone, accR[1]);
    __syncthreads();
    cur ^= 1;
    #pragma unroll
    for (int qi=0; qi<2; ++qi){ bCur[qi][0] = bNxt[qi][0]; bCur[qi][1] = bNxt[qi][1]; }
  }
  #pragma unroll
  for (int qi=0; qi<2; ++qi){
    #pragma unroll
    for (int df=0; df<12; ++df)
      #pragma unroll
      for (int r=0; r<4; ++r){
        int q = q0 + qi*16 + lg*4 + r;
        OP[(((size_t)zi*8 + h)*2048 + q)*192 + df*16 + lr] = f2h(accO[qi][df][r]);
      }
    if (lr == 0)
      #pragma unroll
      for (int r=0; r<4; ++r)
        SP[((size_t)zi*8 + h)*2048 + q0 + qi*16 + lg*4 + r] = accR[qi][r];
  }
}

// ---- combine 4 z-partials -> 64-row fragment-major fp16 A-tiles for gemm3 ----
__global__ __launch_bounds__(256) void k_comb2(const u16* __restrict__ OP,
    const float* __restrict__ SP, u16* __restrict__ Ao2){
  int id = blockIdx.x*256 + threadIdx.x;    // 393216
  int hq = id / 24;
  int oct = id - hq*24;
  int d0 = oct*8;
  float inv = 1.0f / (SP[hq] + SP[16384+hq] + SP[32768+hq] + SP[49152+hq]);
  float o[8] = {0,0,0,0,0,0,0,0};
  #pragma unroll
  for (int z=0; z<4; ++z){
    uint4 v = *(const uint4*)&OP[((size_t)z*16384 + hq)*192 + d0];
    const u16* pv = (const u16*)&v;
    #pragma unroll
    for (int e=0; e<8; ++e) o[e] += h2f(pv[e]);
  }
  int h = hq >> 11, q = hq & 2047;
  int col = h*192 + d0;
  int kt = col>>6, ks2 = (col>>5)&1, lg = (col>>3)&3;
  int mt = q>>6, ms = (q>>4)&3, m16 = q&15;
  int lane = lg*16 + m16;
  u16 hh[8];
  #pragma unroll
  for (int e=0; e<8; ++e) hh[e] = f2h(o[e]*inv);
  size_t base = (size_t)(mt*24 + kt)*4096;
  *(uint4*)&Ao2[base + (size_t)(ks2*4 + ms)*512 + lane*8] = *(uint4*)hh;
}

extern "C" void kernel_launch(void* const* d_in, const int* in_sizes, int n_in,
                              void* d_out, int out_size, void* d_ws, size_t ws_size,
                              hipStream_t stream){
  (void)in_sizes; (void)n_in; (void)out_size; (void)ws_size;
  const float* x   = (const float*)d_in[0];
  const float* pwi = (const float*)d_in[1];
  const float* rot = (const float*)d_in[2];
  const float* Wq  = (const float*)d_in[3];
  const float* qw  = (const float*)d_in[4];
  const float* kw  = (const float*)d_in[5];
  const float* vw  = (const float*)d_in[6];
  const float* gm  = (const float*)d_in[7];
  const float* bt  = (const float*)d_in[8];
  const float* rvv = (const float*)d_in[9];
  const float* Wb  = (const float*)d_in[10];
  const float* Wo  = (const float*)d_in[11];
  float* out = (float*)d_out;
  char* ws = (char*)d_ws;
  size_t off = 0;
  auto alloc = [&](size_t bytes)->char*{
    char* p = ws + off; off = (off + bytes + 255) & ~(size_t)255; return p;
  };
  u16*   Axq = (u16*)alloc(16ull*16*8192*2);      // x frag-major fp16 (4 MB)
  u16*   Bq1 = (u16*)alloc(21ull*16*4096*2);      // Wqkv frag-major fp16 (2.75 MB)
  u16*   Bq2 = (u16*)alloc(16ull*24*4096*2);      // Wo frag-major fp16 (3.1 MB)
  u16*   Ao2 = (u16*)alloc(32ull*24*4096*2);      // attn-out 64-row frag-major (6.3 MB)
  u16*   qkvh = (u16*)alloc(2048ull*1344*2);      // qkv fp16 (5.5 MB)
  u16*   Qfb = (u16*)alloc(8ull*2048*128*2);
  u16*   KVF = (u16*)alloc(64ull*10240*2);
  u16*   biash = (u16*)alloc(8ull*512*512*2);     // bias f16 [pair][8] (4.2 MB)
  u16*   OP  = (u16*)alloc(4ull*8*2048*192*2);
  float* SP  = (float*)alloc(4ull*8*2048*4);

  k_pre<<<1744, 256, 0, stream>>>(x, Wq, Wo, Axq, Bq1, Bq2);
  k_g1b2<<<2384, 256, 0, stream>>>(Axq, Bq1, qkvh, pwi, rvv, gm, bt, Wb, biash);
  k_norm<<<5120, 256, 0, stream>>>(qkvh, rot, qw, kw, vw, Qfb, KVF);
  k_attn6<<<dim3(64, 2, 4), 256, 0, stream>>>(Qfb, KVF, biash, OP, SP);
  k_comb2<<<1536, 256, 0, stream>>>(OP, SP, Ao2);
  k_gemm3<<<512, 256, 0, stream>>>(Ao2, Bq2, out, 1024, 24, 16);
}